// Round 11
// baseline (181.603 us; speedup 1.0000x reference)
//
#include <hip/hip_runtime.h>

#define NB    256   // neighbors
#define DIN   64
#define LATD  128
#define ECD   32

typedef __attribute__((ext_vector_type(8))) __bf16 bf16x8;
typedef __attribute__((ext_vector_type(4))) float f32x4;

#define XS_STRIDE 72   // row stride for WcT/WfT in d_ws (bf16 elems)
#define EC_STRIDE 40   // ec tile row stride (shorts)
#define WA_STRIDE 40
#define XROW_F    68   // xstage row stride in floats (64 + 4 pad; mult of 4 for b128)

// d_ws layout (unsigned short elements)
#define WS_WC 0                     // WcT  [32][72]
#define WS_WF (32 * 72)             // WfT  [128][72]
#define WS_WA (32 * 72 + 128 * 72)  // WaTm [128][40]  (Wa rows 32..63, transposed, *log2e)

#define MFMA(a, b, c) __builtin_amdgcn_mfma_f32_16x16x32_bf16((a), (b), (c), 0, 0, 0)

__device__ __forceinline__ unsigned short f2bf(float f) {
    unsigned u = __builtin_bit_cast(unsigned, f);
    u += 0x7fffu + ((u >> 16) & 1u);   // round-to-nearest-even
    return (unsigned short)(u >> 16);
}

// Packed f32->bf16 RNE: 1 instruction per 2 elements (gfx950; no builtin).
// Plain VALU op -> no TRANS hazard, safe as opaque asm (verified r2..r10).
__device__ __forceinline__ unsigned cvt2(float lo, float hi) {
    unsigned r;
    asm("v_cvt_pk_bf16_f32 %0, %1, %2" : "=v"(r) : "v"(lo), "v"(hi));
    return r;
}

// Single-instruction exp2. r4 LESSON: raw `asm("v_exp_f32")` FAILS (TRANS
// hazard invisible through opaque asm; absmax 1.5). Builtin = same op with
// compiler-managed hazards (r5+ verified).
#if __has_builtin(__builtin_amdgcn_exp2f)
__device__ __forceinline__ float fexp2(float x) {
    return __builtin_amdgcn_exp2f(x);
}
#else
__device__ __forceinline__ float fexp2(float x) {
    float r;
    asm("v_exp_f32 %0, %1\n\ts_nop 1" : "=v"(r) : "v"(x));
    return r;
}
#endif

__device__ __forceinline__ bf16x8 pack8(float4 a, float4 b) {
    union { unsigned u[4]; bf16x8 v; } r;
    r.u[0] = cvt2(a.x, a.y);
    r.u[1] = cvt2(a.z, a.w);
    r.u[2] = cvt2(b.x, b.y);
    r.u[3] = cvt2(b.z, b.w);
    return r.v;
}

// Pre-transpose weights into bf16 B-fragment-friendly [n][k] layouts in d_ws.
// Wa rows 32..63 are pre-scaled by log2e so the kernel can use exp2 directly.
__global__ __launch_bounds__(256) void prep_kernel(
    const float* __restrict__ Wc, const float* __restrict__ Wf,
    const float* __restrict__ Wa, unsigned short* __restrict__ ws)
{
    int t = blockIdx.x * blockDim.x + threadIdx.x;
    int stride = gridDim.x * blockDim.x;
    for (int i = t; i < 32 * 64; i += stride) {
        int n = i >> 6, k = i & 63;
        ws[WS_WC + n * XS_STRIDE + k] = f2bf(Wc[k * ECD + n]);
    }
    for (int i = t; i < 128 * 64; i += stride) {
        int n = i >> 6, k = i & 63;
        ws[WS_WF + n * XS_STRIDE + k] = f2bf(Wf[k * LATD + n]);
    }
    for (int i = t; i < 128 * 32; i += stride) {
        int n = i >> 5, k = i & 31;
        ws[WS_WA + n * WA_STRIDE + k] = f2bf(Wa[(ECD + k) * LATD + n] * 1.44269504f);
    }
}

// r10 post-mortem: arm_main is 41-46us in EVERY measured config (waves 2-8/
// SIMD, weights in L2/LDS/regs, VALU halved) with all pipes <17% -> bound by
// X-delivery rate under the 16-row-scattered dwordx4 gather (~1 TB/s
// effective vs 6.3 streaming). THIS REV: contiguous-load streaming —
// each wave reads its rows as lane-contiguous 1KB/instruction bursts into
// regs, redistributes via a small padded LDS tile, reads MFMA fragments
// back; per-tile pipeline (depth-2 prefetch, t outer / g inner, num[g]
// accumulators in regs). Same math as r10, new ingestion path only.
// All LDS traffic is same-wave (in-order, no barriers until the combine).
// Key algebra (verified): self_rep/mean_rep/ba constant along n -> cancel
// in softmax(axis=n); att = softmax_n(enc_comm @ Wa[32:64]); local_data /
// Wa[0:32] / Wa[64:96] / ba never touch the output.
__global__ __launch_bounds__(256, 2) void arm_main(
    const float* __restrict__ xg,   // neighbor [B][256][64]
    const float* __restrict__ bcv,  // bc [32]
    const float* __restrict__ bfv,  // bf [128]
    const float* __restrict__ wl,   // Wl [128][128]
    const float* __restrict__ blv,  // bl [128]
    const unsigned short* __restrict__ ws,
    float* __restrict__ out)        // [B][128]
{
    __shared__ float xstage[4][2][16 * XROW_F];     // 34816 B [wave][buf][16x68]
    __shared__ unsigned short ecst[4][16 * EC_STRIDE]; // 5120 B per-wave ec tile
    __shared__ float aggnum[2][4][LATD];            // 4096 B
    __shared__ float aggden[2][4][LATD];            // 4096 B
    __shared__ float aggfull[2][LATD];              // 1024 B
    __shared__ float wlpart[2][2][LATD];            // 2048 B
    // total 51200 B -> 2 blocks/CU

    const int b0   = blockIdx.x;          // gridDim.x == 512
    const int b1   = blockIdx.x + 512;
    const int tid  = threadIdx.x;
    const int lane = tid & 63;
    const int w    = tid >> 6;   // wave id, owns rows 64w..64w+63 per element
    const int l15  = lane & 15;
    const int q    = lane >> 4;

    // ---- hoist ALL weights/biases into registers (issued first; latency
    // hides under the X prologue). Wc 4 + per-g 24 frags + bf 8 + bc 2.
    bf16x8 wfrag[2][2];
    #pragma unroll
    for (int ks = 0; ks < 2; ++ks)
        #pragma unroll
        for (int nb = 0; nb < 2; ++nb)
            wfrag[ks][nb] = *reinterpret_cast<const bf16x8*>(
                &ws[WS_WC + (nb * 16 + l15) * XS_STRIDE + ks * 32 + q * 8]);
    bf16x8 wf0g[8], wf1g[8], wagg[8];
    float  bfl8[8];
    #pragma unroll
    for (int g = 0; g < 8; ++g) {
        const int r0 = g * 16 + l15;
        wf0g[g] = *reinterpret_cast<const bf16x8*>(&ws[WS_WF + r0 * XS_STRIDE + q * 8]);
        wf1g[g] = *reinterpret_cast<const bf16x8*>(&ws[WS_WF + r0 * XS_STRIDE + 32 + q * 8]);
        wagg[g] = *reinterpret_cast<const bf16x8*>(&ws[WS_WA + r0 * WA_STRIDE + q * 8]);
        bfl8[g] = bfv[r0];
    }
    float bc0 = bcv[l15], bc1 = bcv[16 + l15];

    // ---- X ingestion: contiguous 1KB-per-instruction wave reads ----
    // Tile s (0..7): elem = s>>2, tile-in-elem = s&3 (16 rows = 4KB).
    // LOADT: lane reads 4 float4 at tilebase + lane*16B + i*1KB (contiguous).
    // DSWRITE: scatter to padded [16][68] rows: float f = i*256+lane*4 ->
    //   row i*4+(lane>>4), col (lane&15)*4 (16B-aligned; ~2-way banks).
    const float* xw0 = xg + (size_t)b0 * NB * DIN + w * 64 * DIN;
    const float* xw1 = xg + (size_t)b1 * NB * DIN + w * 64 * DIN;

    float4 stA[4], stB[4];

#define LOADT(set, s_)                                                        \
    {                                                                         \
        const float* p = ((s_) < 4 ? xw0 : xw1) + ((s_) & 3) * 1024 + lane * 4; \
        set[0] = *reinterpret_cast<const float4*>(p);                         \
        set[1] = *reinterpret_cast<const float4*>(p + 256);                   \
        set[2] = *reinterpret_cast<const float4*>(p + 512);                   \
        set[3] = *reinterpret_cast<const float4*>(p + 768);                   \
    }

#define DSWRITE(set, buf)                                                     \
    {                                                                         \
        float* d = &xstage[w][buf][(lane >> 4) * XROW_F + (lane & 15) * 4];   \
        *reinterpret_cast<float4*>(d + 0 * 4 * XROW_F) = set[0];              \
        *reinterpret_cast<float4*>(d + 1 * 4 * XROW_F) = set[1];              \
        *reinterpret_cast<float4*>(d + 2 * 4 * XROW_F) = set[2];              \
        *reinterpret_cast<float4*>(d + 3 * 4 * XROW_F) = set[3];              \
    }

    // prologue: prime tiles 0,1; tile 0 into LDS buf0
    LOADT(stA, 0);
    LOADT(stB, 1);
    DSWRITE(stA, 0);

    float num[8] = {0.f, 0.f, 0.f, 0.f, 0.f, 0.f, 0.f, 0.f};
    float den[8] = {0.f, 0.f, 0.f, 0.f, 0.f, 0.f, 0.f, 0.f};

    #pragma unroll
    for (int s = 0; s < 8; ++s) {
        // (a) prefetch tile s+2 into the register set whose tile is already
        //     in LDS (even s -> stA, odd s -> stB)
        if (s + 2 < 8) {
            if ((s & 1) == 0) { LOADT(stA, s + 2); }
            else              { LOADT(stB, s + 2); }
        }
        // (b) stage tile s+1 (held in the other set) into buf (s+1)&1
        if (s + 1 < 8) {
            if ((s & 1) == 0) { DSWRITE(stB, (s + 1) & 1); }
            else              { DSWRITE(stA, (s + 1) & 1); }
        }

        // (c) fragments of tile s from LDS (same-wave order guarantees the
        //     DSWRITE of this buf, >=1 step ago, completed)
        const float* xr = &xstage[w][s & 1][l15 * XROW_F + q * 8];
        float4 r0 = *reinterpret_cast<const float4*>(xr);
        float4 r1 = *reinterpret_cast<const float4*>(xr + 4);
        float4 r2 = *reinterpret_cast<const float4*>(xr + 32);
        float4 r3 = *reinterpret_cast<const float4*>(xr + 36);
        bf16x8 xf0 = pack8(r0, r1);
        bf16x8 xf1 = pack8(r2, r3);

        // (d) enc_comm tile: relu(X*Wc + bc) -> ec tile (wave-private LDS)
        f32x4 a0 = {bc0, bc0, bc0, bc0};
        f32x4 a1 = {bc1, bc1, bc1, bc1};
        a0 = MFMA(xf0, wfrag[0][0], a0); a0 = MFMA(xf1, wfrag[1][0], a0);
        a1 = MFMA(xf0, wfrag[0][1], a1); a1 = MFMA(xf1, wfrag[1][1], a1);
        #pragma unroll
        for (int r = 0; r < 4; ++r) {
            int row = q * 4 + r;   // C/D: row = quad*4 + reg (within tile)
            unsigned pk = cvt2(fmaxf(a0[r], 0.f), fmaxf(a1[r], 0.f));
            ecst[w][row * EC_STRIDE + l15]      = (unsigned short)pk;
            ecst[w][row * EC_STRIDE + 16 + l15] = (unsigned short)(pk >> 16);
        }
        bf16x8 ecf = *reinterpret_cast<const bf16x8*>(&ecst[w][l15 * EC_STRIDE + q * 8]);

        // (e) all 8 g for this tile: enc_feature + logits + softmax partials
        #pragma unroll
        for (int g = 0; g < 8; ++g) {
            f32x4 z = {bfl8[g], bfl8[g], bfl8[g], bfl8[g]};  // bf in acc init
            z = MFMA(xf0, wf0g[g], z);
            f32x4 ef = MFMA(xf1, wf1g[g], z);
            f32x4 zz = {0.f, 0.f, 0.f, 0.f};                 // ba cancels
            f32x4 lg = MFMA(ecf, wagg[g], zz);
            #pragma unroll
            for (int r = 0; r < 4; ++r) {
                float ev = fmaxf(ef[r], 0.f);
                float p  = fexp2(lg[r]);    // Wa pre-scaled by log2e in prep
                num[g] = fmaf(p, ev, num[g]);
                den[g] += p;
            }
        }

        // (f) element boundary: reduce across lanes, store partials, reset
        if ((s & 3) == 3) {
            const int e = s >> 2;
            #pragma unroll
            for (int g = 0; g < 8; ++g) {
                float n2 = num[g], d2 = den[g];
                n2 += __shfl_xor(n2, 16, 64); n2 += __shfl_xor(n2, 32, 64);
                d2 += __shfl_xor(d2, 16, 64); d2 += __shfl_xor(d2, 32, 64);
                if (lane < 16) {
                    aggnum[e][w][g * 16 + lane] = n2;
                    aggden[e][w][g * 16 + lane] = d2;
                }
                num[g] = 0.f;
                den[g] = 0.f;
            }
        }
    }
#undef LOADT
#undef DSWRITE
    __syncthreads();

    // ---- combine wave partials (both halves of the block active) ----
    {
        int e = tid >> 7, c = tid & 127;
        float n2 = aggnum[e][0][c] + aggnum[e][1][c] + aggnum[e][2][c] + aggnum[e][3][c];
        float d2 = aggden[e][0][c] + aggden[e][1][c] + aggden[e][2][c] + aggden[e][3][c];
        aggfull[e][c] = n2 / d2;
    }
    __syncthreads();

    // ---- out = relu(agg @ Wl + bl): wl loaded ONCE, used for both elems ----
    {
        int c = tid & 127, h = tid >> 7;
        float acc0 = 0.f, acc1 = 0.f;
        #pragma unroll 16
        for (int k = h * 64; k < h * 64 + 64; ++k) {
            float wv = wl[k * LATD + c];
            acc0 = fmaf(aggfull[0][k], wv, acc0);
            acc1 = fmaf(aggfull[1][k], wv, acc1);
        }
        wlpart[h][0][c] = acc0;
        wlpart[h][1][c] = acc1;
    }
    __syncthreads();
    {
        int e = tid >> 7, c = tid & 127;
        out[(size_t)(e ? b1 : b0) * LATD + c] =
            fmaxf(wlpart[0][e][c] + wlpart[1][e][c] + blv[c], 0.f);
    }
}

extern "C" void kernel_launch(void* const* d_in, const int* in_sizes, int n_in,
                              void* d_out, int out_size, void* d_ws, size_t ws_size,
                              hipStream_t stream)
{
    const float* xg  = (const float*)d_in[1];
    const float* wc  = (const float*)d_in[2];
    const float* bc_ = (const float*)d_in[3];
    const float* wf  = (const float*)d_in[4];
    const float* bf_ = (const float*)d_in[5];
    const float* wa  = (const float*)d_in[6];
    const float* wl  = (const float*)d_in[8];
    const float* bl_ = (const float*)d_in[9];
    unsigned short* wsp = (unsigned short*)d_ws;   // needs 33,280 B of ws
    float* out = (float*)d_out;

    prep_kernel<<<8, 256, 0, stream>>>(wc, wf, wa, wsp);
    arm_main<<<512, 256, 0, stream>>>(xg, bc_, bf_, wl, bl_, wsp, out);
}

// Round 12
// 169.423 us; speedup vs baseline: 1.0719x; 1.0719x over previous
//
#include <hip/hip_runtime.h>

#define NB    256   // neighbors
#define DIN   64
#define LATD  128
#define ECD   32

typedef __attribute__((ext_vector_type(8))) __bf16 bf16x8;
typedef __attribute__((ext_vector_type(4))) float f32x4;

#define XS_STRIDE 72   // row stride for WcT/WfT in d_ws (bf16 elems)
#define EC_STRIDE 40   // ec tile row stride (shorts); (l15*5+q)&7 -> 2-way banks
#define WA_STRIDE 40

// d_ws layout (unsigned short elements)
#define WS_WC 0                     // WcT  [32][72]
#define WS_WF (32 * 72)             // WfT  [128][72]
#define WS_WA (32 * 72 + 128 * 72)  // WaTm [128][40]  (Wa rows 32..63, transposed, *log2e)

#define MFMA(a, b, c) __builtin_amdgcn_mfma_f32_16x16x32_bf16((a), (b), (c), 0, 0, 0)

__device__ __forceinline__ unsigned short f2bf(float f) {
    unsigned u = __builtin_bit_cast(unsigned, f);
    u += 0x7fffu + ((u >> 16) & 1u);   // round-to-nearest-even
    return (unsigned short)(u >> 16);
}

// Packed f32->bf16 RNE (gfx950; no builtin). Plain VALU -> no TRANS hazard.
__device__ __forceinline__ unsigned cvt2(float lo, float hi) {
    unsigned r;
    asm("v_cvt_pk_bf16_f32 %0, %1, %2" : "=v"(r) : "v"(lo), "v"(hi));
    return r;
}

// Single-instruction exp2. r4 LESSON: raw asm v_exp_f32 has an invisible
// TRANS hazard (absmax 1.5); the builtin adds compiler-managed hazards.
#if __has_builtin(__builtin_amdgcn_exp2f)
__device__ __forceinline__ float fexp2(float x) {
    return __builtin_amdgcn_exp2f(x);
}
#else
__device__ __forceinline__ float fexp2(float x) {
    float r;
    asm("v_exp_f32 %0, %1\n\ts_nop 1" : "=v"(r) : "v"(x));
    return r;
}
#endif

__device__ __forceinline__ bf16x8 pack8(float4 a, float4 b) {
    union { unsigned u[4]; bf16x8 v; } r;
    r.u[0] = cvt2(a.x, a.y);
    r.u[1] = cvt2(a.z, a.w);
    r.u[2] = cvt2(b.x, b.y);
    r.u[3] = cvt2(b.z, b.w);
    return r.v;
}

// HBM->LDS direct (width 16): zero VGPR staging cost. LDS dest is
// wave-uniform base + lane*16; global src is per-lane (pre-swizzled).
__device__ __forceinline__ void gload_lds16(const void* g, void* l) {
    __builtin_amdgcn_global_load_lds(
        (const __attribute__((address_space(1))) unsigned int*)g,
        (__attribute__((address_space(3))) unsigned int*)l, 16, 0, 0);
}

// Pre-transpose weights into bf16 B-fragment-friendly [n][k] layouts in d_ws.
// Wa rows 32..63 are pre-scaled by log2e so the kernel can use exp2 directly.
__global__ __launch_bounds__(256) void prep_kernel(
    const float* __restrict__ Wc, const float* __restrict__ Wf,
    const float* __restrict__ Wa, unsigned short* __restrict__ ws)
{
    int t = blockIdx.x * blockDim.x + threadIdx.x;
    int stride = gridDim.x * blockDim.x;
    for (int i = t; i < 32 * 64; i += stride) {
        int n = i >> 6, k = i & 63;
        ws[WS_WC + n * XS_STRIDE + k] = f2bf(Wc[k * ECD + n]);
    }
    for (int i = t; i < 128 * 64; i += stride) {
        int n = i >> 6, k = i & 63;
        ws[WS_WF + n * XS_STRIDE + k] = f2bf(Wf[k * LATD + n]);
    }
    for (int i = t; i < 128 * 32; i += stride) {
        int n = i >> 5, k = i & 31;
        ws[WS_WA + n * WA_STRIDE + k] = f2bf(Wa[(ECD + k) * LATD + n] * 1.44269504f);
    }
}

// r11 post-mortem: contiguous X reads delivered 2.78 TB/s (3.5x the old
// scattered gather) but register staging spilled (WRITE_SIZE 130MB).
// THIS REV: global_load_lds streaming — HBM->LDS direct, zero staging
// registers. Per wave: 8 tiles (16 rows x 256B) double-buffered; global
// source XOR-pre-swizzled so the linear LDS dest equals a swizzled layout;
// frag ds_reads apply the same XOR -> slot (2q)^(row&7), b128-optimal
// (linear would be 16-way). Counted vmcnt(4) keeps next tile's 4 loads
// in flight (T4); lgkmcnt(0) before re-staging a just-read buffer.
// Weights register-hoisted (r10: 120 VGPR, no spill). Math identical to
// r8/r10/r11 (all verified).
// Key algebra (verified): self_rep/mean_rep/ba constant along n -> cancel
// in softmax(axis=n); att = softmax_n(enc_comm @ Wa[32:64]); local_data /
// Wa[0:32] / Wa[64:96] / ba never touch the output.
__global__ __launch_bounds__(256, 2) void arm_main(
    const float* __restrict__ xg,   // neighbor [B][256][64]
    const float* __restrict__ bcv,  // bc [32]
    const float* __restrict__ bfv,  // bf [128]
    const float* __restrict__ wl,   // Wl [128][128]
    const float* __restrict__ blv,  // bl [128]
    const unsigned short* __restrict__ ws,
    float* __restrict__ out)        // [B][128]
{
    __shared__ float xstage[4][2][1024];               // 32768 B [wave][buf][16x256B]
    __shared__ unsigned short ecst[4][16 * EC_STRIDE]; // 5120 B per-wave ec tile
    __shared__ float aggnum[2][4][LATD];               // 4096 B
    __shared__ float aggden[2][4][LATD];               // 4096 B
    __shared__ float aggfull[2][LATD];                 // 1024 B
    __shared__ float wlpart[2][2][LATD];               // 2048 B
    // total 49152 B -> 2 blocks/CU

    const int b0   = blockIdx.x;          // gridDim.x == 512
    const int b1   = blockIdx.x + 512;
    const int tid  = threadIdx.x;
    const int lane = tid & 63;
    const int w    = tid >> 6;   // wave id, owns rows 64w..64w+63 per element
    const int l15  = lane & 15;
    const int q    = lane >> 4;

    // ---- hoist ALL weights/biases into registers (r10-proven; latency
    // hides under the staging prologue). 122 VGPR of loop-invariant state.
    bf16x8 wfrag[2][2];
    #pragma unroll
    for (int ks = 0; ks < 2; ++ks)
        #pragma unroll
        for (int nb = 0; nb < 2; ++nb)
            wfrag[ks][nb] = *reinterpret_cast<const bf16x8*>(
                &ws[WS_WC + (nb * 16 + l15) * XS_STRIDE + ks * 32 + q * 8]);
    bf16x8 wf0g[8], wf1g[8], wagg[8];
    float  bfl8[8];
    #pragma unroll
    for (int g = 0; g < 8; ++g) {
        const int r0 = g * 16 + l15;
        wf0g[g] = *reinterpret_cast<const bf16x8*>(&ws[WS_WF + r0 * XS_STRIDE + q * 8]);
        wf1g[g] = *reinterpret_cast<const bf16x8*>(&ws[WS_WF + r0 * XS_STRIDE + 32 + q * 8]);
        wagg[g] = *reinterpret_cast<const bf16x8*>(&ws[WS_WA + r0 * WA_STRIDE + q * 8]);
        bfl8[g] = bfv[r0];
    }
    float bc0 = bcv[l15], bc1 = bcv[16 + l15];

    // ---- staging: tile s (0..7): elem = s>>2, 16-row chunk = s&3 (4KB).
    // Linear LDS off Li = i*1024 + lane*16; row = i*4 + q (tile-local).
    // Global src = Li ^ ((row&7)<<4)  (involution; rule 21 both-sides swz).
    const float* xw0 = xg + (size_t)b0 * NB * DIN + w * 64 * DIN;
    const float* xw1 = xg + (size_t)b1 * NB * DIN + w * 64 * DIN;

#define STAGE(s_)                                                             \
    {                                                                         \
        const char* tb = (const char*)(((s_) < 4 ? xw0 : xw1) + ((s_) & 3) * 1024); \
        float* lb = &xstage[w][(s_) & 1][0];                                  \
        _Pragma("unroll")                                                     \
        for (int i = 0; i < 4; ++i) {                                         \
            unsigned off = (unsigned)(i * 1024 + lane * 16);                  \
            unsigned r7  = (unsigned)((i * 4 + q) & 7);                       \
            gload_lds16(tb + (off ^ (r7 << 4)), lb + i * 256);                \
        }                                                                     \
    }

    // prologue: prime tiles 0 (buf0) and 1 (buf1)
    STAGE(0);
    STAGE(1);

    float num[8] = {0.f, 0.f, 0.f, 0.f, 0.f, 0.f, 0.f, 0.f};
    float den[8] = {0.f, 0.f, 0.f, 0.f, 0.f, 0.f, 0.f, 0.f};

    // frag read offsets (swizzled): base o0 = (l15*256 + q*32) ^ ((l15&7)<<4);
    // +16 / +128 toggles live in untouched bits -> XOR composition is exact.
    const unsigned o0 = ((unsigned)(l15 * 256 + q * 32)) ^ ((unsigned)(l15 & 7) << 4);

    #pragma unroll
    for (int s = 0; s < 8; ++s) {
        // (1) tile s resident: all but the newest 4 vmem ops (tile s+1) done
        if (s < 7) { asm volatile("s_waitcnt vmcnt(4)" ::: "memory"); }
        else       { asm volatile("s_waitcnt vmcnt(0)" ::: "memory"); }

        // (2) fragment reads (4 x ds_read_b128, conflict-optimal via swizzle)
        const char* xb = (const char*)&xstage[w][s & 1][0];
        float4 r0 = *reinterpret_cast<const float4*>(xb + o0);
        float4 r1 = *reinterpret_cast<const float4*>(xb + (o0 ^ 16));
        float4 r2 = *reinterpret_cast<const float4*>(xb + (o0 ^ 128));
        float4 r3 = *reinterpret_cast<const float4*>(xb + (o0 ^ 144));

        // (3) reads retired -> safe to overwrite this buffer with tile s+2
        asm volatile("s_waitcnt lgkmcnt(0)" ::: "memory");
        if (s + 2 < 8) { STAGE(s + 2); }

        bf16x8 xf0 = pack8(r0, r1);
        bf16x8 xf1 = pack8(r2, r3);

        // (4) enc_comm tile: relu(X*Wc + bc) -> ec tile (wave-private LDS;
        // same-wave DS ordering, no barrier). Bias folded into acc init.
        f32x4 a0 = {bc0, bc0, bc0, bc0};
        f32x4 a1 = {bc1, bc1, bc1, bc1};
        a0 = MFMA(xf0, wfrag[0][0], a0); a0 = MFMA(xf1, wfrag[1][0], a0);
        a1 = MFMA(xf0, wfrag[0][1], a1); a1 = MFMA(xf1, wfrag[1][1], a1);
        #pragma unroll
        for (int r = 0; r < 4; ++r) {
            int row = q * 4 + r;   // C/D: row = quad*4 + reg (tile-local)
            unsigned pk = cvt2(fmaxf(a0[r], 0.f), fmaxf(a1[r], 0.f));
            ecst[w][row * EC_STRIDE + l15]      = (unsigned short)pk;
            ecst[w][row * EC_STRIDE + 16 + l15] = (unsigned short)(pk >> 16);
        }
        bf16x8 ecf = *reinterpret_cast<const bf16x8*>(&ecst[w][l15 * EC_STRIDE + q * 8]);

        // (5) all 8 g for this tile: enc_feature + logits + softmax partials
        #pragma unroll
        for (int g = 0; g < 8; ++g) {
            f32x4 z = {bfl8[g], bfl8[g], bfl8[g], bfl8[g]};  // bf in acc init
            z = MFMA(xf0, wf0g[g], z);
            f32x4 ef = MFMA(xf1, wf1g[g], z);
            f32x4 zz = {0.f, 0.f, 0.f, 0.f};                 // ba cancels
            f32x4 lg = MFMA(ecf, wagg[g], zz);
            #pragma unroll
            for (int r = 0; r < 4; ++r) {
                float ev = fmaxf(ef[r], 0.f);
                float p  = fexp2(lg[r]);    // Wa pre-scaled by log2e in prep
                num[g] = fmaf(p, ev, num[g]);
                den[g] += p;
            }
        }

        // (6) element boundary: reduce across lanes, store partials, reset
        if ((s & 3) == 3) {
            const int e = s >> 2;
            #pragma unroll
            for (int g = 0; g < 8; ++g) {
                float n2 = num[g], d2 = den[g];
                n2 += __shfl_xor(n2, 16, 64); n2 += __shfl_xor(n2, 32, 64);
                d2 += __shfl_xor(d2, 16, 64); d2 += __shfl_xor(d2, 32, 64);
                if (lane < 16) {
                    aggnum[e][w][g * 16 + lane] = n2;
                    aggden[e][w][g * 16 + lane] = d2;
                }
                num[g] = 0.f;
                den[g] = 0.f;
            }
        }
    }
#undef STAGE
    __syncthreads();

    // ---- combine wave partials (both halves of the block active) ----
    {
        int e = tid >> 7, c = tid & 127;
        float n2 = aggnum[e][0][c] + aggnum[e][1][c] + aggnum[e][2][c] + aggnum[e][3][c];
        float d2 = aggden[e][0][c] + aggden[e][1][c] + aggden[e][2][c] + aggden[e][3][c];
        aggfull[e][c] = n2 / d2;
    }
    __syncthreads();

    // ---- out = relu(agg @ Wl + bl): wl loaded ONCE, used for both elems ----
    {
        int c = tid & 127, h = tid >> 7;
        float acc0 = 0.f, acc1 = 0.f;
        #pragma unroll 16
        for (int k = h * 64; k < h * 64 + 64; ++k) {
            float wv = wl[k * LATD + c];
            acc0 = fmaf(aggfull[0][k], wv, acc0);
            acc1 = fmaf(aggfull[1][k], wv, acc1);
        }
        wlpart[h][0][c] = acc0;
        wlpart[h][1][c] = acc1;
    }
    __syncthreads();
    {
        int e = tid >> 7, c = tid & 127;
        out[(size_t)(e ? b1 : b0) * LATD + c] =
            fmaxf(wlpart[0][e][c] + wlpart[1][e][c] + blv[c], 0.f);
    }
}

extern "C" void kernel_launch(void* const* d_in, const int* in_sizes, int n_in,
                              void* d_out, int out_size, void* d_ws, size_t ws_size,
                              hipStream_t stream)
{
    const float* xg  = (const float*)d_in[1];
    const float* wc  = (const float*)d_in[2];
    const float* bc_ = (const float*)d_in[3];
    const float* wf  = (const float*)d_in[4];
    const float* bf_ = (const float*)d_in[5];
    const float* wa  = (const float*)d_in[6];
    const float* wl  = (const float*)d_in[8];
    const float* bl_ = (const float*)d_in[9];
    unsigned short* wsp = (unsigned short*)d_ws;   // needs 33,280 B of ws
    float* out = (float*)d_out;

    prep_kernel<<<8, 256, 0, stream>>>(wc, wf, wa, wsp);
    arm_main<<<512, 256, 0, stream>>>(xg, bc_, bf_, wl, bl_, wsp, out);
}

// Round 13
// 121.887 us; speedup vs baseline: 1.4899x; 1.3900x over previous
//
#include <hip/hip_runtime.h>

#define NB    256   // neighbors
#define DIN   64
#define LATD  128
#define ECD   32

typedef __attribute__((ext_vector_type(8))) __bf16 bf16x8;
typedef __attribute__((ext_vector_type(4))) float f32x4;

#define XS_STRIDE 72   // row stride for WcT/WfT (bf16 elems)
#define EC_STRIDE 40   // ec tile row stride (shorts)
#define WA_STRIDE 40

// d_ws layout (unsigned short elements)
#define WS_WC 0                     // WcT  [32][72]
#define WS_WF (32 * 72)             // WfT  [128][72]
#define WS_WA (32 * 72 + 128 * 72)  // WaTm [128][40]  (Wa rows 32..63, transposed, *log2e)
// WfT and WaTm contiguous: one 14336-short (28672 B) staging chunk.
#define WSTAGE_SHORTS (128 * 72 + 128 * 40)
#define WA_OFF (128 * 72)           // offset of WaTm inside the staged chunk

#define MFMA(a, b, c) __builtin_amdgcn_mfma_f32_16x16x32_bf16((a), (b), (c), 0, 0, 0)

__device__ __forceinline__ unsigned short f2bf(float f) {
    unsigned u = __builtin_bit_cast(unsigned, f);
    u += 0x7fffu + ((u >> 16) & 1u);   // round-to-nearest-even
    return (unsigned short)(u >> 16);
}

// Packed f32->bf16 RNE (gfx950; no builtin). Plain VALU -> no TRANS hazard.
__device__ __forceinline__ unsigned cvt2(float lo, float hi) {
    unsigned r;
    asm("v_cvt_pk_bf16_f32 %0, %1, %2" : "=v"(r) : "v"(lo), "v"(hi));
    return r;
}

// Single-instruction exp2. r4 LESSON: raw asm v_exp_f32 has an invisible
// TRANS hazard (absmax 1.5); the builtin adds compiler-managed hazards.
#if __has_builtin(__builtin_amdgcn_exp2f)
__device__ __forceinline__ float fexp2(float x) {
    return __builtin_amdgcn_exp2f(x);
}
#else
__device__ __forceinline__ float fexp2(float x) {
    float r;
    asm("v_exp_f32 %0, %1\n\ts_nop 1" : "=v"(r) : "v"(x));
    return r;
}
#endif

__device__ __forceinline__ bf16x8 pack8(float4 a, float4 b) {
    union { unsigned u[4]; bf16x8 v; } r;
    r.u[0] = cvt2(a.x, a.y);
    r.u[1] = cvt2(a.z, a.w);
    r.u[2] = cvt2(b.x, b.y);
    r.u[3] = cvt2(b.z, b.w);
    return r.v;
}

// HBM->LDS direct (width 16): zero VGPR staging cost. LDS dest is
// wave-uniform base + lane*16; global src is per-lane (pre-swizzled).
__device__ __forceinline__ void gload_lds16(const void* g, void* l) {
    __builtin_amdgcn_global_load_lds(
        (const __attribute__((address_space(1))) unsigned int*)g,
        (__attribute__((address_space(3))) unsigned int*)l, 16, 0, 0);
}

// Pre-transpose weights into bf16 B-fragment-friendly [n][k] layouts in d_ws.
// Wa rows 32..63 are pre-scaled by log2e so the kernel can use exp2 directly.
__global__ __launch_bounds__(256) void prep_kernel(
    const float* __restrict__ Wc, const float* __restrict__ Wf,
    const float* __restrict__ Wa, unsigned short* __restrict__ ws)
{
    int t = blockIdx.x * blockDim.x + threadIdx.x;
    int stride = gridDim.x * blockDim.x;
    for (int i = t; i < 32 * 64; i += stride) {
        int n = i >> 6, k = i & 63;
        ws[WS_WC + n * XS_STRIDE + k] = f2bf(Wc[k * ECD + n]);
    }
    for (int i = t; i < 128 * 64; i += stride) {
        int n = i >> 6, k = i & 63;
        ws[WS_WF + n * XS_STRIDE + k] = f2bf(Wf[k * LATD + n]);
    }
    for (int i = t; i < 128 * 32; i += stride) {
        int n = i >> 5, k = i & 31;
        ws[WS_WA + n * WA_STRIDE + k] = f2bf(Wa[(ECD + k) * LATD + n] * 1.44269504f);
    }
}

// r12 post-mortem: contiguous gload_lds delivered 2.6 TB/s (vs 0.8-1.5 for
// the scattered gather -> r8's 43.6us IS 67MB/1.54TB/s delivery-bound) but
// 112-VGPR hoisted weights + fully-unrolled s-loop spilled (WRITE 99MB).
// THIS REV strips pressure: weights back in LDS (r8-proven), DYNAMIC
// s-loop (unroll 1), single-buffered xstage with issue-early staging:
//   vmcnt(0) -> ds_read frags -> lgkmcnt(0) -> STAGE(s+1) -> compute(s)
// so the next iteration's vmcnt(0) is already satisfied (~1800cy of compute
// between issue and wait) — depth-1 pipeline without double-buffering.
// Ingestion math identical to r12 (PASSED bit-exact).
// Key algebra (verified): self_rep/mean_rep/ba constant along n -> cancel
// in softmax(axis=n); att = softmax_n(enc_comm @ Wa[32:64]); local_data /
// Wa[0:32] / Wa[64:96] / ba never touch the output.
__global__ __launch_bounds__(256, 2) void arm_main(
    const float* __restrict__ xg,   // neighbor [B][256][64]
    const float* __restrict__ bcv,  // bc [32]
    const float* __restrict__ bfv,  // bf [128]
    const float* __restrict__ wl,   // Wl [128][128]
    const float* __restrict__ blv,  // bl [128]
    const unsigned short* __restrict__ ws,
    float* __restrict__ out)        // [B][128]
{
    __shared__ unsigned short wstage[WSTAGE_SHORTS];   // 28672 B: WfT + WaTm
    __shared__ float bfs[LATD];                        // 512 B
    __shared__ float xstage[4][1024];                  // 16384 B [wave][16 rows x 256B]
    __shared__ unsigned short ecst[4][16 * EC_STRIDE]; // 5120 B per-wave ec tile
    __shared__ float aggnum[2][4][LATD];               // 4096 B
    __shared__ float aggden[2][4][LATD];               // 4096 B
    __shared__ float aggfull[2][LATD];                 // 1024 B
    __shared__ float wlpart[2][2][LATD];               // 2048 B
    // total 61952 B (< 64 KB static cap) -> 2 blocks/CU

    const int b0   = blockIdx.x;          // gridDim.x == 512
    const int b1   = blockIdx.x + 512;
    const int tid  = threadIdx.x;
    const int lane = tid & 63;
    const int w    = tid >> 6;   // wave id, owns rows 64w..64w+63 per element
    const int l15  = lane & 15;
    const int q    = lane >> 4;

    // ---- issue weight-staging loads (L2) first: 7 uint4/thread + bf ----
    uint4 wch[7];
    {
        const uint4* src = reinterpret_cast<const uint4*>(ws + WS_WF);
        #pragma unroll
        for (int i = 0; i < 7; ++i)
            wch[i] = src[tid + i * 256];
    }
    uint4 bfch;
    if (tid < 32) bfch = reinterpret_cast<const uint4*>(bfv)[tid];

    // ---- element-invariant: Wc frags + bc (L2, registers; 16+2 VGPR) ----
    bf16x8 wfrag[2][2];
    #pragma unroll
    for (int ks = 0; ks < 2; ++ks)
        #pragma unroll
        for (int nb = 0; nb < 2; ++nb)
            wfrag[ks][nb] = *reinterpret_cast<const bf16x8*>(
                &ws[WS_WC + (nb * 16 + l15) * XS_STRIDE + ks * 32 + q * 8]);
    float bc0 = bcv[l15], bc1 = bcv[16 + l15];

    // ---- staging: tile s (0..7): elem = s>>2, 16-row chunk = s&3 (4KB).
    // Linear LDS off Li = i*1024 + lane*16; row = i*4 + q (tile-local).
    // Global src = Li ^ ((row&7)<<4)  (involution; verified bit-exact r12).
    const float* xw0 = xg + (size_t)b0 * NB * DIN + w * 64 * DIN;
    const float* xw1 = xg + (size_t)b1 * NB * DIN + w * 64 * DIN;

#define STAGE(s_)                                                             \
    {                                                                         \
        const char* tb = (const char*)(((s_) < 4 ? xw0 : xw1) + ((s_) & 3) * 1024); \
        float* lb = &xstage[w][0];                                            \
        _Pragma("unroll")                                                     \
        for (int i = 0; i < 4; ++i) {                                         \
            unsigned off = (unsigned)(i * 1024 + lane * 16);                  \
            unsigned r7  = (unsigned)((i * 4 + q) & 7);                       \
            gload_lds16(tb + (off ^ (r7 << 4)), lb + i * 256);                \
        }                                                                     \
    }

    STAGE(0);

    // ---- write staged weights to LDS (counted wait on wch only — they were
    // issued before STAGE(0) in the in-order vmem queue), then barrier.
    {
        uint4* dst = reinterpret_cast<uint4*>(wstage);
        #pragma unroll
        for (int i = 0; i < 7; ++i)
            dst[tid + i * 256] = wch[i];
        if (tid < 32) reinterpret_cast<uint4*>(bfs)[tid] = bfch;
    }
    __syncthreads();   // weights visible to all waves (also drains STAGE(0))

    float num[8] = {0.f, 0.f, 0.f, 0.f, 0.f, 0.f, 0.f, 0.f};
    float den[8] = {0.f, 0.f, 0.f, 0.f, 0.f, 0.f, 0.f, 0.f};

    // frag read offsets (swizzled): o0 = (l15*256 + q*32) ^ ((l15&7)<<4);
    // +16/+128/+144 toggles live in untouched bits -> XOR composition exact.
    const unsigned o0 = ((unsigned)(l15 * 256 + q * 32)) ^ ((unsigned)(l15 & 7) << 4);

    #pragma unroll 1
    for (int s = 0; s < 8; ++s) {
        // (1) tile s resident (its 4 loads are the only outstanding vmem)
        asm volatile("s_waitcnt vmcnt(0)" ::: "memory");

        // (2) fragment reads (4 x ds_read_b128, conflict-free via swizzle)
        const char* xb = (const char*)&xstage[w][0];
        float4 r0 = *reinterpret_cast<const float4*>(xb + o0);
        float4 r1 = *reinterpret_cast<const float4*>(xb + (o0 ^ 16));
        float4 r2 = *reinterpret_cast<const float4*>(xb + (o0 ^ 128));
        float4 r3 = *reinterpret_cast<const float4*>(xb + (o0 ^ 144));

        // (3) reads fully retired -> safe to overwrite buffer with tile s+1;
        // issued BEFORE compute so its ~900cy hides under ~1800cy of math.
        asm volatile("s_waitcnt lgkmcnt(0)" ::: "memory");
        if (s < 7) { STAGE(s + 1); }

        bf16x8 xf0 = pack8(r0, r1);
        bf16x8 xf1 = pack8(r2, r3);

        // (4) enc_comm tile: relu(X*Wc + bc) -> ec tile (wave-private LDS;
        // same-wave DS ordering, no barrier). Bias folded into acc init.
        f32x4 a0 = {bc0, bc0, bc0, bc0};
        f32x4 a1 = {bc1, bc1, bc1, bc1};
        a0 = MFMA(xf0, wfrag[0][0], a0); a0 = MFMA(xf1, wfrag[1][0], a0);
        a1 = MFMA(xf0, wfrag[0][1], a1); a1 = MFMA(xf1, wfrag[1][1], a1);
        #pragma unroll
        for (int r = 0; r < 4; ++r) {
            int row = q * 4 + r;   // C/D: row = quad*4 + reg (tile-local)
            unsigned pk = cvt2(fmaxf(a0[r], 0.f), fmaxf(a1[r], 0.f));
            ecst[w][row * EC_STRIDE + l15]      = (unsigned short)pk;
            ecst[w][row * EC_STRIDE + 16 + l15] = (unsigned short)(pk >> 16);
        }
        bf16x8 ecf = *reinterpret_cast<const bf16x8*>(&ecst[w][l15 * EC_STRIDE + q * 8]);

        // (5) all 8 g for this tile; weights from LDS per g (r8-proven path)
        #pragma unroll
        for (int g = 0; g < 8; ++g) {
            const int rw = g * 16 + l15;
            bf16x8 wf0 = *reinterpret_cast<const bf16x8*>(&wstage[rw * XS_STRIDE + q * 8]);
            bf16x8 wf1 = *reinterpret_cast<const bf16x8*>(&wstage[rw * XS_STRIDE + 32 + q * 8]);
            bf16x8 wag = *reinterpret_cast<const bf16x8*>(&wstage[WA_OFF + rw * WA_STRIDE + q * 8]);
            float  bfl = bfs[rw];

            f32x4 z = {bfl, bfl, bfl, bfl};   // bf bias in acc init
            z = MFMA(xf0, wf0, z);
            f32x4 ef = MFMA(xf1, wf1, z);
            f32x4 zz = {0.f, 0.f, 0.f, 0.f};  // ba cancels
            f32x4 lg = MFMA(ecf, wag, zz);
            #pragma unroll
            for (int r = 0; r < 4; ++r) {
                float ev = fmaxf(ef[r], 0.f);
                float p  = fexp2(lg[r]);      // Wa pre-scaled by log2e
                num[g] = fmaf(p, ev, num[g]);
                den[g] += p;
            }
        }

        // (6) element boundary: reduce across lanes, store partials, reset
        if ((s & 3) == 3) {
            const int e = s >> 2;
            #pragma unroll
            for (int g = 0; g < 8; ++g) {
                float n2 = num[g], d2 = den[g];
                n2 += __shfl_xor(n2, 16, 64); n2 += __shfl_xor(n2, 32, 64);
                d2 += __shfl_xor(d2, 16, 64); d2 += __shfl_xor(d2, 32, 64);
                if (lane < 16) {
                    aggnum[e][w][g * 16 + lane] = n2;
                    aggden[e][w][g * 16 + lane] = d2;
                }
                num[g] = 0.f;
                den[g] = 0.f;
            }
        }
    }
#undef STAGE
    __syncthreads();

    // ---- combine wave partials (both halves of the block active) ----
    {
        int e = tid >> 7, c = tid & 127;
        float n2 = aggnum[e][0][c] + aggnum[e][1][c] + aggnum[e][2][c] + aggnum[e][3][c];
        float d2 = aggden[e][0][c] + aggden[e][1][c] + aggden[e][2][c] + aggden[e][3][c];
        aggfull[e][c] = n2 / d2;
    }
    __syncthreads();

    // ---- out = relu(agg @ Wl + bl): wl loaded ONCE, used for both elems ----
    {
        int c = tid & 127, h = tid >> 7;
        float acc0 = 0.f, acc1 = 0.f;
        #pragma unroll 16
        for (int k = h * 64; k < h * 64 + 64; ++k) {
            float wv = wl[k * LATD + c];
            acc0 = fmaf(aggfull[0][k], wv, acc0);
            acc1 = fmaf(aggfull[1][k], wv, acc1);
        }
        wlpart[h][0][c] = acc0;
        wlpart[h][1][c] = acc1;
    }
    __syncthreads();
    {
        int e = tid >> 7, c = tid & 127;
        out[(size_t)(e ? b1 : b0) * LATD + c] =
            fmaxf(wlpart[0][e][c] + wlpart[1][e][c] + blv[c], 0.f);
    }
}

extern "C" void kernel_launch(void* const* d_in, const int* in_sizes, int n_in,
                              void* d_out, int out_size, void* d_ws, size_t ws_size,
                              hipStream_t stream)
{
    const float* xg  = (const float*)d_in[1];
    const float* wc  = (const float*)d_in[2];
    const float* bc_ = (const float*)d_in[3];
    const float* wf  = (const float*)d_in[4];
    const float* bf_ = (const float*)d_in[5];
    const float* wa  = (const float*)d_in[6];
    const float* wl  = (const float*)d_in[8];
    const float* bl_ = (const float*)d_in[9];
    unsigned short* wsp = (unsigned short*)d_ws;   // needs 33,280 B of ws
    float* out = (float*)d_out;

    prep_kernel<<<8, 256, 0, stream>>>(wc, wf, wa, wsp);
    arm_main<<<512, 256, 0, stream>>>(xg, bc_, bf_, wl, bl_, wsp, out);
}

// Round 14
// 121.736 us; speedup vs baseline: 1.4918x; 1.0012x over previous
//
#include <hip/hip_runtime.h>

#define NB    256   // neighbors
#define DIN   64
#define LATD  128
#define ECD   32

typedef __attribute__((ext_vector_type(8))) __bf16 bf16x8;
typedef __attribute__((ext_vector_type(4))) float f32x4;

#define XS_STRIDE 72   // row stride for WcT/WfT in d_ws (bf16 elems)
#define EC_STRIDE 40   // ec tile row stride (shorts)
#define WA_STRIDE 40

// d_ws layout (unsigned short elements)
#define WS_WC 0                     // WcT  [32][72]
#define WS_WF (32 * 72)             // WfT  [128][72]
#define WS_WA (32 * 72 + 128 * 72)  // WaTm [128][40]  (Wa rows 32..63, transposed, *log2e)

#define MFMA(a, b, c) __builtin_amdgcn_mfma_f32_16x16x32_bf16((a), (b), (c), 0, 0, 0)

__device__ __forceinline__ unsigned short f2bf(float f) {
    unsigned u = __builtin_bit_cast(unsigned, f);
    u += 0x7fffu + ((u >> 16) & 1u);   // round-to-nearest-even
    return (unsigned short)(u >> 16);
}

// Packed f32->bf16 RNE (gfx950; no builtin). Plain VALU -> no TRANS hazard.
__device__ __forceinline__ unsigned cvt2(float lo, float hi) {
    unsigned r;
    asm("v_cvt_pk_bf16_f32 %0, %1, %2" : "=v"(r) : "v"(lo), "v"(hi));
    return r;
}

// Single-instruction exp2. r4 LESSON: raw asm v_exp_f32 has an invisible
// TRANS hazard (absmax 1.5); the builtin adds compiler-managed hazards.
#if __has_builtin(__builtin_amdgcn_exp2f)
__device__ __forceinline__ float fexp2(float x) {
    return __builtin_amdgcn_exp2f(x);
}
#else
__device__ __forceinline__ float fexp2(float x) {
    float r;
    asm("v_exp_f32 %0, %1\n\ts_nop 1" : "=v"(r) : "v"(x));
    return r;
}
#endif

__device__ __forceinline__ bf16x8 pack8(float4 a, float4 b) {
    union { unsigned u[4]; bf16x8 v; } r;
    r.u[0] = cvt2(a.x, a.y);
    r.u[1] = cvt2(a.z, a.w);
    r.u[2] = cvt2(b.x, b.y);
    r.u[3] = cvt2(b.z, b.w);
    return r.v;
}

// HBM->LDS direct (width 16): zero VGPR staging cost. LDS dest is
// wave-uniform base + lane*16; global src is per-lane (pre-swizzled).
__device__ __forceinline__ void gload_lds16(const void* g, void* l) {
    __builtin_amdgcn_global_load_lds(
        (const __attribute__((address_space(1))) unsigned int*)g,
        (__attribute__((address_space(3))) unsigned int*)l, 16, 0, 0);
}

// Pre-transpose weights into bf16 B-fragment-friendly [n][k] layouts in d_ws.
// Wa rows 32..63 are pre-scaled by log2e so the kernel can use exp2 directly.
__global__ __launch_bounds__(256) void prep_kernel(
    const float* __restrict__ Wc, const float* __restrict__ Wf,
    const float* __restrict__ Wa, unsigned short* __restrict__ ws)
{
    int t = blockIdx.x * blockDim.x + threadIdx.x;
    int stride = gridDim.x * blockDim.x;
    for (int i = t; i < 32 * 64; i += stride) {
        int n = i >> 6, k = i & 63;
        ws[WS_WC + n * XS_STRIDE + k] = f2bf(Wc[k * ECD + n]);
    }
    for (int i = t; i < 128 * 64; i += stride) {
        int n = i >> 6, k = i & 63;
        ws[WS_WF + n * XS_STRIDE + k] = f2bf(Wf[k * LATD + n]);
    }
    for (int i = t; i < 128 * 32; i += stride) {
        int n = i >> 5, k = i & 31;
        ws[WS_WA + n * WA_STRIDE + k] = f2bf(Wa[(ECD + k) * LATD + n] * 1.44269504f);
    }
}

// r13 post-mortem: streaming gload_lds ingestion is correct + spill-free and
// moved the plateau (123.5 -> 121.9 wall). Remaining chain: 64x per wave of
// {3 ds_read_b128 weights -> lgkmcnt -> MFMA} with 2 waves/SIMD. THIS REV:
// the untested combination — per-g weights in REGISTERS (r10: clean at 120
// VGPR) + DYNAMIC s-loop (r12's spill was the unrolled loop, not the
// weights) + streaming ingestion; wstage freed -> xstage double-buffered
// (counted vmcnt(4), 2 compute phases of HBM cover). g-loop is now pure
// register math. Est ~220 VGPR < 256 cap; WRITE_SIZE is the spill canary.
// Key algebra (verified): self_rep/mean_rep/ba constant along n -> cancel
// in softmax(axis=n); att = softmax_n(enc_comm @ Wa[32:64]); local_data /
// Wa[0:32] / Wa[64:96] / ba never touch the output.
__global__ __launch_bounds__(256, 2) void arm_main(
    const float* __restrict__ xg,   // neighbor [B][256][64]
    const float* __restrict__ bcv,  // bc [32]
    const float* __restrict__ bfv,  // bf [128]
    const float* __restrict__ wl,   // Wl [128][128]
    const float* __restrict__ blv,  // bl [128]
    const unsigned short* __restrict__ ws,
    float* __restrict__ out)        // [B][128]
{
    __shared__ float xstage[4][2][1024];               // 32768 B [wave][buf][16x256B]
    __shared__ unsigned short ecst[4][16 * EC_STRIDE]; // 5120 B per-wave ec tile
    __shared__ float aggnum[2][4][LATD];               // 4096 B
    __shared__ float aggden[2][4][LATD];               // 4096 B
    __shared__ float aggfull[2][LATD];                 // 1024 B
    __shared__ float wlpart[2][2][LATD];               // 2048 B
    // total 49152 B -> 2 blocks/CU (LDS 160KB/CU; VGPR is the binder)

    const int b0   = blockIdx.x;          // gridDim.x == 512
    const int b1   = blockIdx.x + 512;
    const int tid  = threadIdx.x;
    const int lane = tid & 63;
    const int w    = tid >> 6;   // wave id, owns rows 64w..64w+63 per element
    const int l15  = lane & 15;
    const int q    = lane >> 4;

    // ---- hoist ALL weights/biases into registers, issued FIRST so the
    // counted vmcnt below (which also covers them) is exact, and their
    // ~300cy L2 latency hides under the staging prologue. 112+18 VGPR.
    bf16x8 wf0g[8], wf1g[8], wagg[8];
    float  bfl8[8];
    #pragma unroll
    for (int g = 0; g < 8; ++g) {
        const int r0 = g * 16 + l15;
        wf0g[g] = *reinterpret_cast<const bf16x8*>(&ws[WS_WF + r0 * XS_STRIDE + q * 8]);
        wf1g[g] = *reinterpret_cast<const bf16x8*>(&ws[WS_WF + r0 * XS_STRIDE + 32 + q * 8]);
        wagg[g] = *reinterpret_cast<const bf16x8*>(&ws[WS_WA + r0 * WA_STRIDE + q * 8]);
        bfl8[g] = bfv[r0];
    }
    bf16x8 wfrag[2][2];
    #pragma unroll
    for (int ks = 0; ks < 2; ++ks)
        #pragma unroll
        for (int nb = 0; nb < 2; ++nb)
            wfrag[ks][nb] = *reinterpret_cast<const bf16x8*>(
                &ws[WS_WC + (nb * 16 + l15) * XS_STRIDE + ks * 32 + q * 8]);
    float bc0 = bcv[l15], bc1 = bcv[16 + l15];

    // ---- staging: tile s (0..7): elem = s>>2, 16-row chunk = s&3 (4KB).
    // Linear LDS off Li = i*1024 + lane*16; row = i*4 + q (tile-local).
    // Global src = Li ^ ((row&7)<<4)  (involution; verified bit-exact r12/r13).
    const float* xw0 = xg + (size_t)b0 * NB * DIN + w * 64 * DIN;
    const float* xw1 = xg + (size_t)b1 * NB * DIN + w * 64 * DIN;

#define STAGE(s_)                                                             \
    {                                                                         \
        const char* tb = (const char*)(((s_) < 4 ? xw0 : xw1) + ((s_) & 3) * 1024); \
        float* lb = &xstage[w][(s_) & 1][0];                                  \
        _Pragma("unroll")                                                     \
        for (int i = 0; i < 4; ++i) {                                         \
            unsigned off = (unsigned)(i * 1024 + lane * 16);                  \
            unsigned r7  = (unsigned)((i * 4 + q) & 7);                       \
            gload_lds16(tb + (off ^ (r7 << 4)), lb + i * 256);                \
        }                                                                     \
    }

    // prologue: prime tiles 0 (buf0) and 1 (buf1)
    STAGE(0);
    STAGE(1);

    float num[8] = {0.f, 0.f, 0.f, 0.f, 0.f, 0.f, 0.f, 0.f};
    float den[8] = {0.f, 0.f, 0.f, 0.f, 0.f, 0.f, 0.f, 0.f};

    // frag read offsets (swizzled): o0 = (l15*256 + q*32) ^ ((l15&7)<<4);
    // +16/+128/+144 toggles live in untouched bits -> XOR composition exact.
    const unsigned o0 = ((unsigned)(l15 * 256 + q * 32)) ^ ((unsigned)(l15 & 7) << 4);

    #pragma unroll 1
    for (int s = 0; s < 8; ++s) {
        // (1) tile s resident: everything except tile s+1's 4 loads done
        //     (weight loads precede STAGE(0) in the in-order vmem queue,
        //     so vmcnt(4) also guarantees the register weights are live).
        if (s < 7) { asm volatile("s_waitcnt vmcnt(4)" ::: "memory"); }
        else       { asm volatile("s_waitcnt vmcnt(0)" ::: "memory"); }

        // (2) fragment reads (4 x ds_read_b128, conflict-free via swizzle)
        const char* xb = (const char*)&xstage[w][s & 1][0];
        float4 r0 = *reinterpret_cast<const float4*>(xb + o0);
        float4 r1 = *reinterpret_cast<const float4*>(xb + (o0 ^ 16));
        float4 r2 = *reinterpret_cast<const float4*>(xb + (o0 ^ 128));
        float4 r3 = *reinterpret_cast<const float4*>(xb + (o0 ^ 144));

        // (3) reads retired -> safe to overwrite this buffer with tile s+2;
        //     issued BEFORE compute so ~2 compute phases cover its latency.
        asm volatile("s_waitcnt lgkmcnt(0)" ::: "memory");
        if (s + 2 < 8) { STAGE(s + 2); }

        bf16x8 xf0 = pack8(r0, r1);
        bf16x8 xf1 = pack8(r2, r3);

        // (4) enc_comm tile: relu(X*Wc + bc) -> ec tile (wave-private LDS;
        // same-wave DS ordering, no barrier). Bias folded into acc init.
        f32x4 a0 = {bc0, bc0, bc0, bc0};
        f32x4 a1 = {bc1, bc1, bc1, bc1};
        a0 = MFMA(xf0, wfrag[0][0], a0); a0 = MFMA(xf1, wfrag[1][0], a0);
        a1 = MFMA(xf0, wfrag[0][1], a1); a1 = MFMA(xf1, wfrag[1][1], a1);
        #pragma unroll
        for (int r = 0; r < 4; ++r) {
            int row = q * 4 + r;   // C/D: row = quad*4 + reg (tile-local)
            unsigned pk = cvt2(fmaxf(a0[r], 0.f), fmaxf(a1[r], 0.f));
            ecst[w][row * EC_STRIDE + l15]      = (unsigned short)pk;
            ecst[w][row * EC_STRIDE + 16 + l15] = (unsigned short)(pk >> 16);
        }
        bf16x8 ecf = *reinterpret_cast<const bf16x8*>(&ecst[w][l15 * EC_STRIDE + q * 8]);

        // (5) all 8 g for this tile: PURE register math (weights hoisted) —
        // no loads of any kind inside this loop.
        #pragma unroll
        for (int g = 0; g < 8; ++g) {
            f32x4 z = {bfl8[g], bfl8[g], bfl8[g], bfl8[g]};  // bf in acc init
            z = MFMA(xf0, wf0g[g], z);
            f32x4 ef = MFMA(xf1, wf1g[g], z);
            f32x4 zz = {0.f, 0.f, 0.f, 0.f};                 // ba cancels
            f32x4 lg = MFMA(ecf, wagg[g], zz);
            #pragma unroll
            for (int r = 0; r < 4; ++r) {
                float ev = fmaxf(ef[r], 0.f);
                float p  = fexp2(lg[r]);    // Wa pre-scaled by log2e in prep
                num[g] = fmaf(p, ev, num[g]);
                den[g] += p;
            }
        }

        // (6) element boundary: reduce across lanes, store partials, reset
        if ((s & 3) == 3) {
            const int e = s >> 2;
            #pragma unroll
            for (int g = 0; g < 8; ++g) {
                float n2 = num[g], d2 = den[g];
                n2 += __shfl_xor(n2, 16, 64); n2 += __shfl_xor(n2, 32, 64);
                d2 += __shfl_xor(d2, 16, 64); d2 += __shfl_xor(d2, 32, 64);
                if (lane < 16) {
                    aggnum[e][w][g * 16 + lane] = n2;
                    aggden[e][w][g * 16 + lane] = d2;
                }
                num[g] = 0.f;
                den[g] = 0.f;
            }
        }
    }
#undef STAGE
    __syncthreads();

    // ---- combine wave partials (both halves of the block active) ----
    {
        int e = tid >> 7, c = tid & 127;
        float n2 = aggnum[e][0][c] + aggnum[e][1][c] + aggnum[e][2][c] + aggnum[e][3][c];
        float d2 = aggden[e][0][c] + aggden[e][1][c] + aggden[e][2][c] + aggden[e][3][c];
        aggfull[e][c] = n2 / d2;
    }
    __syncthreads();

    // ---- out = relu(agg @ Wl + bl): wl loaded ONCE, used for both elems ----
    {
        int c = tid & 127, h = tid >> 7;
        float acc0 = 0.f, acc1 = 0.f;
        #pragma unroll 16
        for (int k = h * 64; k < h * 64 + 64; ++k) {
            float wv = wl[k * LATD + c];
            acc0 = fmaf(aggfull[0][k], wv, acc0);
            acc1 = fmaf(aggfull[1][k], wv, acc1);
        }
        wlpart[h][0][c] = acc0;
        wlpart[h][1][c] = acc1;
    }
    __syncthreads();
    {
        int e = tid >> 7, c = tid & 127;
        out[(size_t)(e ? b1 : b0) * LATD + c] =
            fmaxf(wlpart[0][e][c] + wlpart[1][e][c] + blv[c], 0.f);
    }
}

extern "C" void kernel_launch(void* const* d_in, const int* in_sizes, int n_in,
                              void* d_out, int out_size, void* d_ws, size_t ws_size,
                              hipStream_t stream)
{
    const float* xg  = (const float*)d_in[1];
    const float* wc  = (const float*)d_in[2];
    const float* bc_ = (const float*)d_in[3];
    const float* wf  = (const float*)d_in[4];
    const float* bf_ = (const float*)d_in[5];
    const float* wa  = (const float*)d_in[6];
    const float* wl  = (const float*)d_in[8];
    const float* bl_ = (const float*)d_in[9];
    unsigned short* wsp = (unsigned short*)d_ws;   // needs 33,280 B of ws
    float* out = (float*)d_out;

    prep_kernel<<<8, 256, 0, stream>>>(wc, wf, wa, wsp);
    arm_main<<<512, 256, 0, stream>>>(xg, bc_, bf_, wl, bl_, wsp, out);
}